// Round 7
// baseline (246.457 us; speedup 1.0000x reference)
//
#include <hip/hip_runtime.h>
#include <math.h>

#define T_TOK 2048
#define HIDDEN 2048
#define NH 16
#define NKV 8
#define DH 128

typedef unsigned short u16;
typedef __attribute__((ext_vector_type(8))) short bf16x8;
typedef __attribute__((ext_vector_type(4))) float f32x4;

__device__ __forceinline__ u16 f2bf(float f) {
  union { float f; unsigned u; } x; x.f = f;
  unsigned r = (x.u + 0x7fffu + ((x.u >> 16) & 1u)) >> 16;
  return (u16)r;
}

__device__ __forceinline__ float bf2f(u16 v) {
  union { unsigned u; float f; } x; x.u = ((unsigned)v) << 16;
  return x.f;
}

__device__ __forceinline__ void gload16(const void* g, void* l) {
  __builtin_amdgcn_global_load_lds((const __attribute__((address_space(1))) void*)g,
                                   (__attribute__((address_space(3))) void*)l,
                                   16, 0, 0);
}

// -------------------------------------------------------------- fused prepass
// b < 4096            : hidden fp32 -> bf16 (Xb)
// 4096 <= b < 6144    : transpose w_qkv [2048][4096] -> WqkvT bf16 [4096][2048]
// 6144 <= b < 7168    : transpose w_o  [2048][2048] -> WoT  bf16 [2048][2048]
__global__ __launch_bounds__(256) void prepass(const float* __restrict__ hidden,
                                               const float* __restrict__ w_qkv,
                                               const float* __restrict__ w_o,
                                               u16* __restrict__ Xb,
                                               u16* __restrict__ WqkvT,
                                               u16* __restrict__ WoT) {
  __shared__ float tile[64][65];
  const int b = blockIdx.x;
  if (b < 4096) {
    int i = b * 256 + threadIdx.x;
    float4 v = ((const float4*)hidden)[i];
    ushort4 o;
    o.x = f2bf(v.x); o.y = f2bf(v.y); o.z = f2bf(v.z); o.w = f2bf(v.w);
    ((ushort4*)Xb)[i] = o;
    return;
  }
  const float* in; u16* out; int R, Cdim, c0, r0;
  if (b < 6144) {
    int bb = b - 4096;
    in = w_qkv; out = WqkvT; R = 2048; Cdim = 4096;
    c0 = (bb & 63) * 64; r0 = (bb >> 6) * 64;
  } else {
    int bb = b - 6144;
    in = w_o; out = WoT; R = 2048; Cdim = 2048;
    c0 = (bb & 31) * 64; r0 = (bb >> 5) * 64;
  }
  const int tx = threadIdx.x & 63, ty = threadIdx.x >> 6;
#pragma unroll
  for (int i = 0; i < 64; i += 4)
    tile[ty + i][tx] = in[(size_t)(r0 + ty + i) * Cdim + c0 + tx];
  __syncthreads();
#pragma unroll
  for (int i = 0; i < 64; i += 4)
    out[(size_t)(c0 + ty + i) * R + r0 + tx] = f2bf(tile[tx][ty + i]);
}

// sum 2 bf16 partial buffers -> fp32 out
__global__ __launch_bounds__(256) void add_parts2(const u16* __restrict__ a,
                                                  const u16* __restrict__ b,
                                                  float* __restrict__ o, int n4) {
  int i = blockIdx.x * blockDim.x + threadIdx.x;
  if (i < n4) {
    ushort4 x = ((const ushort4*)a)[i], y = ((const ushort4*)b)[i];
    float4 z;
    z.x = bf2f(x.x) + bf2f(y.x);
    z.y = bf2f(x.y) + bf2f(y.y);
    z.z = bf2f(x.z) + bf2f(y.z);
    z.w = bf2f(x.w) + bf2f(y.w);
    ((float4*)o)[i] = z;
  }
}

// ------------------------------------- fused RMSNorm+RoPE and V-transpose
// V is written k-PERMUTED within each 64-token tile (sigma-inv) so the attn
// PV B-fragment (pi contraction order) is one contiguous b128 LDS read.
__global__ __launch_bounds__(256) void rope_vt(const u16* __restrict__ qkv,
                                               const int* __restrict__ pos,
                                               const float* __restrict__ qw,
                                               const float* __restrict__ kw,
                                               u16* __restrict__ Qg,
                                               u16* __restrict__ Kg,
                                               u16* __restrict__ Vt,
                                               unsigned* __restrict__ counter) {
  __shared__ float tile[64][65];
  const int b = blockIdx.x;
  if (b < 12288) {
    const int wave = threadIdx.x >> 6, j = threadIdx.x & 63;
    const int idx = b * 4 + wave;
    const int t = idx & 2047, slot = idx >> 11;
    const float QSC = 0.088388347648318447f * 1.4426950408889634f; // scale*log2e
    const size_t base_i = (size_t)t * 4096 + slot * 128;
    float x1 = bf2f(qkv[base_i + j]);
    float x2 = bf2f(qkv[base_i + j + 64]);
    float ss = x1 * x1 + x2 * x2;
#pragma unroll
    for (int m = 1; m < 64; m <<= 1) ss += __shfl_xor(ss, m);
    float r = rsqrtf(ss * (1.0f / 128.0f) + 1e-6f);
    const bool isq = slot < NH;
    const float* w = isq ? qw : kw;
    float xn1 = x1 * r * w[j], xn2 = x2 * r * w[j + 64];
    float fp = (float)pos[t];
    float inv_freq = exp2f(-(float)j * (13.287712379549449f / 64.0f)); // 10000^(-j/64)
    float ang = fp * inv_freq;
    float sn, cs;
    sincosf(ang, &sn, &cs);
    float o1 = xn1 * cs - xn2 * sn;
    float o2 = xn2 * cs + xn1 * sn;
    if (isq) {
      size_t base = ((size_t)slot * T_TOK + t) * DH;
      Qg[base + j] = f2bf(o1 * QSC); Qg[base + 64 + j] = f2bf(o2 * QSC);
    } else {
      size_t base = ((size_t)(slot - NH) * T_TOK + t) * DH;
      Kg[base + j] = f2bf(o1); Kg[base + 64 + j] = f2bf(o2);
    }
    return;
  }
  if (b == 12288 && threadIdx.x == 0) *counter = 0u;
  const int bb = b - 12288;
  const int h = bb & 7, rest = bb >> 3;
  const int t0 = (rest & 31) * 64, d0 = (rest >> 5) * 64;
  const int tx = threadIdx.x & 63, ty = threadIdx.x >> 6;
#pragma unroll
  for (int i = 0; i < 64; i += 4) {
    size_t gi = (size_t)(t0 + ty + i) * 4096 + (NH + NKV) * DH + h * DH + d0 + tx;
    tile[ty + i][tx] = bf2f(qkv[gi]);
  }
  __syncthreads();
  // sigma-inv: output position tx holds original k-index sx within the tile
  const int sx = ((tx >> 5) * 2 + ((tx >> 2) & 1)) * 16 + ((tx >> 3) & 3) * 4 + (tx & 3);
#pragma unroll
  for (int i = 0; i < 64; i += 4)
    Vt[((size_t)h * DH + d0 + ty + i) * T_TOK + t0 + tx] = f2bf(tile[sx][ty + i]);
}

// ------------------------------------------------------------- GEMM 128x256
// (unchanged — verified counted-vmcnt pipeline)
__global__ __launch_bounds__(512, 2) void gemm128x256(const u16* __restrict__ A,
                                                      const u16* __restrict__ Bt,
                                                      void* __restrict__ Cout,
                                                      int M, int N, int K,
                                                      int lda, int ldb, int obf16) {
  __shared__ __attribute__((aligned(128))) char lds[98304];

  const int nx = N >> 8, ny = M >> 7;
  const int flat = blockIdx.x;
  const int per = gridDim.x >> 3;
  const int swz = (flat & 7) * per + (flat >> 3);
  const int by = swz % ny;
  const int rest = swz / ny;
  const int bx = rest % nx;
  const int bz = rest / nx;
  const int m0 = by << 7, n0 = bx << 8;
  A += (size_t)bz * K;
  Bt += (size_t)bz * K;

  const int tid = threadIdx.x;
  const int wave = tid >> 6, lane = tid & 63;
  const int l15 = lane & 15, quad = lane >> 4;
  const int wr = wave >> 2, wc = wave & 3;

  size_t aoff;
  {
    int chunk = tid;
    int line = chunk >> 3;
    int ls8 = (chunk & 7) ^ (line & 7);
    int row = line * 2 + (ls8 >> 2);
    int ks = ls8 & 3;
    aoff = (size_t)(m0 + row) * lda + ks * 8;
  }
  size_t boff[2];
#pragma unroll
  for (int c = 0; c < 2; ++c) {
    int chunk = c * 512 + tid;
    int line = chunk >> 3;
    int ls8 = (chunk & 7) ^ (line & 7);
    int row = line * 2 + (ls8 >> 2);
    int ks = ls8 & 3;
    boff[c] = (size_t)(n0 + row) * ldb + ks * 8;
  }

#define STAGE(tt) do {                                                   \
    char* da = lds + ((tt) & 3) * 8192 + wave * 1024;                    \
    char* db = lds + 32768 + ((tt) & 3) * 16384 + wave * 1024;           \
    const int kk = (tt) * 32;                                            \
    gload16(A + aoff + kk, da);                                          \
    gload16(Bt + boff[0] + kk, db);                                      \
    gload16(Bt + boff[1] + kk, db + 8192);                               \
  } while (0)

  const int fragoff = (l15 >> 1) * 128 +
                      (((((l15 & 1) << 2) | quad) ^ ((l15 >> 1) & 7)) << 4);

  const f32x4 zero = {0.f, 0.f, 0.f, 0.f};
  f32x4 acc[4][4];
#pragma unroll
  for (int i = 0; i < 4; ++i)
#pragma unroll
    for (int j = 0; j < 4; ++j) acc[i][j] = zero;

  const int NT = K >> 5;
  STAGE(0); STAGE(1); STAGE(2);
  asm volatile("s_waitcnt vmcnt(6)" ::: "memory");
  __builtin_amdgcn_s_barrier();

  for (int t = 0; t < NT; ++t) {
    const char* As = lds + (t & 3) * 8192 + wr * 4096 + fragoff;
    const char* Bs = lds + 32768 + (t & 3) * 16384 + wc * 4096 + fragoff;
    bf16x8 af[4], bfr[4];
#pragma unroll
    for (int mt = 0; mt < 4; ++mt) af[mt] = *(const bf16x8*)(As + mt * 1024);
#pragma unroll
    for (int nt = 0; nt < 4; ++nt) bfr[nt] = *(const bf16x8*)(Bs + nt * 1024);

    if (t + 3 < NT) STAGE(t + 3);

    __builtin_amdgcn_s_setprio(1);
#pragma unroll
    for (int mt = 0; mt < 4; ++mt)
#pragma unroll
      for (int nt = 0; nt < 4; ++nt)
        acc[mt][nt] = __builtin_amdgcn_mfma_f32_16x16x32_bf16(af[mt], bfr[nt], acc[mt][nt], 0, 0, 0);
    __builtin_amdgcn_s_setprio(0);

    const int rem = NT - 1 - t;
    if (rem >= 3)      asm volatile("s_waitcnt vmcnt(6)" ::: "memory");
    else if (rem == 2) asm volatile("s_waitcnt vmcnt(3)" ::: "memory");
    else if (rem == 1) asm volatile("s_waitcnt vmcnt(0)" ::: "memory");
    if (rem > 0) __builtin_amdgcn_s_barrier();
  }
#undef STAGE

  if (obf16) {
    u16* C = (u16*)Cout + (size_t)bz * M * N;
#pragma unroll
    for (int mt = 0; mt < 4; ++mt)
#pragma unroll
      for (int nt = 0; nt < 4; ++nt)
#pragma unroll
        for (int r = 0; r < 4; ++r)
          C[(size_t)(m0 + wr * 64 + mt * 16 + quad * 4 + r) * N + n0 + wc * 64 + nt * 16 + l15] =
              f2bf(acc[mt][nt][r]);
  } else {
    float* C = (float*)Cout + (size_t)bz * M * N;
#pragma unroll
    for (int mt = 0; mt < 4; ++mt)
#pragma unroll
      for (int nt = 0; nt < 4; ++nt)
#pragma unroll
        for (int r = 0; r < 4; ++r)
          C[(size_t)(m0 + wr * 64 + mt * 16 + quad * 4 + r) * N + n0 + wc * 64 + nt * 16 + l15] =
              acc[mt][nt][r];
  }
}

// ------------------------------------------------------------- flash attn
// BM=128, 8 waves (512 thr): one 32KB K/V staging serves 128 q-rows (2x reuse
// vs BM=64), tile-steps 8448->4352, 16 waves/CU. Per-wave math identical to
// the verified R6 kernel: swapped QK^T, in-register pi-packed P (no P LDS),
// V k-permuted in global so PV vf is one conflict-free b128 read.
// Items: 768 = 16 h x [8 qt>=8 x 4-way + 8 qt<8 x 2-way], LPT queue.
__global__ __launch_bounds__(512) void attn_kernel(const u16* __restrict__ Qg,
                                                   const u16* __restrict__ Kg,
                                                   const u16* __restrict__ Vtg,
                                                   float* __restrict__ Opart,
                                                   float* __restrict__ Lpart,
                                                   unsigned* __restrict__ counter) {
  __shared__ u16 Klds[2][64 * 128];    // [s][d], 16B group g at g^(s&15)
  __shared__ u16 Vlds[2][128 * 64];    // [d][p], 16B group g at g^(d&7), p = pi-order
  __shared__ unsigned item_s;
  const int wave = threadIdx.x >> 6, lane = threadIdx.x & 63;
  const int l15 = lane & 15, quad = lane >> 4;
  const f32x4 zero = {0.f, 0.f, 0.f, 0.f};

#define STAGEKV(jj, sl) do {                                            \
    u16* Kd = &Klds[sl][0]; u16* Vd = &Vlds[sl][0];                     \
    _Pragma("unroll")                                                   \
    for (int c = 0; c < 2; ++c) {                                       \
      int chunk = wave * 2 + c;                                         \
      int sL = chunk * 64 + lane;                                       \
      { int ss = sL >> 4;                                               \
        int g = (sL & 15) ^ (ss & 15);                                  \
        gload16(Kh + ((size_t)((jj) * 64 + ss)) * DH + g * 8, Kd + chunk * 512); } \
      { int d = sL >> 3;                                                \
        int g = (sL & 7) ^ (d & 7);                                     \
        gload16(Vh + (size_t)d * T_TOK + (jj) * 64 + g * 8, Vd + chunk * 512); } \
    } } while (0)

  for (;;) {
    __syncthreads();                    // protect item_s + LDS reuse
    if (threadIdx.x == 0) item_s = atomicAdd(counter, 1u);
    __syncthreads();
    const unsigned item = item_s;
    if (item >= 768u) break;
    const int h = (int)item & 15;
    const int qxs = (int)(item >> 4);
    int qt, s, shf;
    if (qxs < 32) { qt = 15 - (qxs >> 2); s = qxs & 3; shf = 2; }
    else { int q2 = qxs - 32; qt = 7 - (q2 >> 1); s = q2 & 1; shf = 1; }
    const int n = 2 * qt + 2;
    const int j0 = (n * s) >> shf;      // never empty: n>=18 for 4-way, n>=2 for 2-way
    const int j1 = (n * (s + 1)) >> shf;
    const int slot = (int)item;
    const int kvh = h >> 1;

    float* Oslot = Opart + (size_t)slot * (128 * 128);

    const u16* Qh = Qg + (size_t)h * T_TOK * DH;
    const u16* Kh = Kg + (size_t)kvh * T_TOK * DH;
    const u16* Vh = Vtg + (size_t)kvh * DH * T_TOK;
    const int qrow0 = qt * 128 + wave * 16;
    const int jq = qrow0 >> 6;          // first k-tile needing causal mask

    bf16x8 qf[4];
#pragma unroll
    for (int ks = 0; ks < 4; ++ks)
      qf[ks] = *(const bf16x8*)(Qh + (size_t)(qrow0 + l15) * DH + ks * 32 + quad * 8);

    f32x4 oacc[8];
#pragma unroll
    for (int i = 0; i < 8; ++i) oacc[i] = zero;
    float l_acc = 0.f;                  // partial l for q=l15 over this lane's k-slots

    // prologue: stage first tile, drain, make visible
    STAGEKV(j0, 0);
    asm volatile("s_waitcnt vmcnt(0)" ::: "memory");
    __builtin_amdgcn_s_barrier();

    for (int j = j0; j < j1; ++j) {
      const int sl = (j - j0) & 1;
      const bool more = (j + 1 < j1);
      if (more) STAGEKV(j + 1, sl ^ 1); // issue-early into other slot
      const u16* Kl = &Klds[sl][0];
      const u16* Vl = &Vlds[sl][0];

      // S' = K (Q*scale*log2e)^T : sacc[nt][r] = S[k=j*64+nt*16+quad*4+r][q=qrow0+l15]
      f32x4 sacc[4];
#pragma unroll
      for (int nt = 0; nt < 4; ++nt) sacc[nt] = zero;
      __builtin_amdgcn_s_setprio(1);
#pragma unroll
      for (int nt = 0; nt < 4; ++nt) {
        int sr = nt * 16 + l15;
#pragma unroll
        for (int ks = 0; ks < 4; ++ks) {
          bf16x8 kf = *(const bf16x8*)&Kl[sr * 128 + (((ks * 4 + quad) ^ (sr & 15)) * 8)];
          sacc[nt] = __builtin_amdgcn_mfma_f32_16x16x32_bf16(kf, qf[ks], sacc[nt], 0, 0, 0);
        }
      }
      __builtin_amdgcn_s_setprio(0);

      if (j >= jq) {                    // causal mask (covers partial AND full tiles)
        int q = qrow0 + l15;
#pragma unroll
        for (int nt = 0; nt < 4; ++nt)
#pragma unroll
          for (int r = 0; r < 4; ++r) {
            int k = j * 64 + nt * 16 + quad * 4 + r;
            if (k > q) sacc[nt][r] = -INFINITY;
          }
      }

      // P = exp2(S') truncated to bf16, packed IN REGISTERS as PV A-frags.
      // pa[ks] slot e holds P[q=l15][k = (ks*2+(e>>2))*16 + quad*4 + (e&3)].
      union { unsigned d[4]; bf16x8 v; } pa[2];
#pragma unroll
      for (int ks = 0; ks < 2; ++ks)
#pragma unroll
        for (int w = 0; w < 4; ++w) {
          int nt = ks * 2 + (w >> 1), rp = (w & 1) * 2;
          unsigned ulo = __float_as_uint(exp2f(sacc[nt][rp]));
          unsigned uhi = __float_as_uint(exp2f(sacc[nt][rp + 1]));
          l_acc += __uint_as_float(ulo & 0xffff0000u) + __uint_as_float(uhi & 0xffff0000u);
          pa[ks].d[w] = (ulo >> 16) | (uhi & 0xffff0000u);
        }

      // O += P V; V content already pi-permuted -> single b128 per fragment
      __builtin_amdgcn_s_setprio(1);
#pragma unroll
      for (int ot = 0; ot < 8; ++ot) {
        int d = ot * 16 + l15;
#pragma unroll
        for (int ks = 0; ks < 2; ++ks) {
          bf16x8 vf = *(const bf16x8*)&Vl[d * 64 + (((ks * 4 + quad) ^ (d & 7)) * 8)];
          oacc[ot] = __builtin_amdgcn_mfma_f32_16x16x32_bf16(pa[ks].v, vf, oacc[ot], 0, 0, 0);
        }
      }
      __builtin_amdgcn_s_setprio(0);

      if (more) {                       // next tile landed; make visible
        asm volatile("s_waitcnt vmcnt(0)" ::: "memory");
        __builtin_amdgcn_s_barrier();
      }
    }

    // epilogue: UNNORMALIZED O; l reduced across the 4 quads (q = l15)
#pragma unroll
    for (int ot = 0; ot < 8; ++ot)
#pragma unroll
      for (int r = 0; r < 4; ++r)
        Oslot[(wave * 16 + quad * 4 + r) * 128 + ot * 16 + l15] = oacc[ot][r];
    l_acc += __shfl_xor(l_acc, 16);
    l_acc += __shfl_xor(l_acc, 32);
    if (quad == 0)
      Lpart[slot * 128 + wave * 16 + l15] = l_acc;
  }
#undef STAGEKV
}

// merge the 2-or-4 KV splits: O = sum(Os) / sum(ls). 256 blocks = (h, qt128)
__global__ __launch_bounds__(256) void attn_merge(const float* __restrict__ Opart,
                                                  const float* __restrict__ Lpart,
                                                  u16* __restrict__ Og) {
  const int b = blockIdx.x;
  const int h = b & 15, qt = b >> 4;
  int ns, base_qxs;
  if (qt >= 8) { ns = 4; base_qxs = (15 - qt) * 4; }
  else         { ns = 2; base_qxs = 32 + (7 - qt) * 2; }
  int sl[4];
#pragma unroll
  for (int s = 0; s < 4; ++s)
    sl[s] = (base_qxs + (s < ns ? s : 0)) * 16 + h;
#pragma unroll
  for (int it = 0; it < 16; ++it) {
    int idx = it * 256 + threadIdx.x;   // 0..4095 float4s (128 rows x 32)
    int r = idx >> 5, c4 = idx & 31;
    float L = Lpart[sl[0] * 128 + r] + Lpart[sl[1] * 128 + r];
    float4 a = ((const float4*)(Opart + (size_t)sl[0] * 16384))[idx];
    float4 c = ((const float4*)(Opart + (size_t)sl[1] * 16384))[idx];
    float4 acc;
    acc.x = a.x + c.x; acc.y = a.y + c.y; acc.z = a.z + c.z; acc.w = a.w + c.w;
    if (ns == 4) {
      L += Lpart[sl[2] * 128 + r] + Lpart[sl[3] * 128 + r];
      float4 e = ((const float4*)(Opart + (size_t)sl[2] * 16384))[idx];
      float4 f = ((const float4*)(Opart + (size_t)sl[3] * 16384))[idx];
      acc.x += e.x + f.x; acc.y += e.y + f.y; acc.z += e.z + f.z; acc.w += e.w + f.w;
    }
    float rl = 1.0f / L;
    int row = qt * 128 + r, col = c4 * 4;
    u16* dst = Og + (size_t)row * (NH * DH) + h * DH + col;
    dst[0] = f2bf(acc.x * rl);
    dst[1] = f2bf(acc.y * rl);
    dst[2] = f2bf(acc.z * rl);
    dst[3] = f2bf(acc.w * rl);
  }
}

// ------------------------------------------------------------------ launch
extern "C" void kernel_launch(void* const* d_in, const int* in_sizes, int n_in,
                              void* d_out, int out_size, void* d_ws, size_t ws_size,
                              hipStream_t stream) {
  (void)in_sizes; (void)n_in; (void)out_size; (void)ws_size;
  const int* positions = (const int*)d_in[0];
  const float* hidden  = (const float*)d_in[1];
  const float* w_qkv   = (const float*)d_in[2];
  const float* w_o     = (const float*)d_in[3];
  const float* q_norm  = (const float*)d_in[4];
  const float* k_norm  = (const float*)d_in[5];
  float* out = (float*)d_out;

  char* ws = (char*)d_ws;                             // peak use 88 MiB
  u16*   Xb    = (u16*)(ws);                          //  8 MiB [dead after GEMM1]
  u16*   WqkvT = (u16*)(ws + ( 8ull << 20));          // 16 MiB [dead after GEMM1]
  u16*   WoT   = (u16*)(ws + (24ull << 20));          //  8 MiB [live till GEMM2]
  u16*   P0    = (u16*)(ws + (32ull << 20));          // 16 MiB: GEMM1 bf16 out (no split)
  // after GEMM1, WqkvT region dead -> Q/K/V live there:
  u16*   Qg    = (u16*)(ws + ( 8ull << 20));          //  8 MiB bf16 [NH][T][D]
  u16*   Kg    = (u16*)(ws + (16ull << 20));          //  4 MiB bf16 [NKV][T][D]
  u16*   Vt    = (u16*)(ws + (20ull << 20));          //  4 MiB bf16 [NKV][D][T] (k-permuted)
  u16*   AttnO = (u16*)(ws + (80ull << 20));          //  8 MiB bf16 [T][NH*D]
  // after rope_vt, P0 dead -> Opart spans [32,80): 768 slots x 64 KB = 48 MiB
  float* Opart = (float*)(ws + (32ull << 20));
  float* Lpart = (float*)(ws);                        // 384 KB, in dead Xb
  unsigned* ctr = (unsigned*)(ws + (512ull << 10));   // 4 B, in dead Xb
  u16*   G2P   = (u16*)(ws + (32ull << 20));          // 16 MiB: GEMM2 bf16 partials (2 x 8 MiB)

  prepass<<<dim3(7168), 256, 0, stream>>>(hidden, w_qkv, w_o, Xb, WqkvT, WoT);

  // QKV proj: 128x256 tiles, NO split-K -> 16x16 = 256 blocks (1/CU)
  gemm128x256<<<dim3(256), 512, 0, stream>>>(
      Xb, WqkvT, P0, T_TOK, 4096, HIDDEN, HIDDEN, HIDDEN, 1);

  rope_vt<<<dim3(12288 + 512), 256, 0, stream>>>(P0, positions,
                                                 q_norm, k_norm, Qg, Kg, Vt, ctr);

  attn_kernel<<<dim3(512), 512, 0, stream>>>(Qg, Kg, Vt, Opart, Lpart, ctr);
  attn_merge<<<dim3(256), 256, 0, stream>>>(Opart, Lpart, AttnO);

  // O-proj: 128x256 tiles, split-K=2 -> 16x8x2 = 256 blocks (1/CU)
  gemm128x256<<<dim3(256), 512, 0, stream>>>(
      AttnO, WoT, G2P, T_TOK, HIDDEN, 1024, NH * DH, NH * DH, 1);
  const int n4 = T_TOK * HIDDEN / 4;
  add_parts2<<<dim3(n4 / 256), 256, 0, stream>>>(
      G2P, G2P + (size_t)T_TOK * HIDDEN, out, n4);
}

// Round 8
// 235.836 us; speedup vs baseline: 1.0450x; 1.0450x over previous
//
#include <hip/hip_runtime.h>
#include <math.h>

#define T_TOK 2048
#define HIDDEN 2048
#define NH 16
#define NKV 8
#define DH 128

typedef unsigned short u16;
typedef __attribute__((ext_vector_type(8))) short bf16x8;
typedef __attribute__((ext_vector_type(4))) float f32x4;

__device__ __forceinline__ u16 f2bf(float f) {
  union { float f; unsigned u; } x; x.f = f;
  unsigned r = (x.u + 0x7fffu + ((x.u >> 16) & 1u)) >> 16;
  return (u16)r;
}

__device__ __forceinline__ float bf2f(u16 v) {
  union { unsigned u; float f; } x; x.u = ((unsigned)v) << 16;
  return x.f;
}

__device__ __forceinline__ void gload16(const void* g, void* l) {
  __builtin_amdgcn_global_load_lds((const __attribute__((address_space(1))) void*)g,
                                   (__attribute__((address_space(3))) void*)l,
                                   16, 0, 0);
}

// -------------------------------------------------------------- fused prepass
// b < 4096            : hidden fp32 -> bf16 (Xb)
// 4096 <= b < 6144    : transpose w_qkv [2048][4096] -> WqkvT bf16 [4096][2048]
// 6144 <= b < 7168    : transpose w_o  [2048][2048] -> WoT  bf16 [2048][2048]
__global__ __launch_bounds__(256) void prepass(const float* __restrict__ hidden,
                                               const float* __restrict__ w_qkv,
                                               const float* __restrict__ w_o,
                                               u16* __restrict__ Xb,
                                               u16* __restrict__ WqkvT,
                                               u16* __restrict__ WoT) {
  __shared__ float tile[64][65];
  const int b = blockIdx.x;
  if (b < 4096) {
    int i = b * 256 + threadIdx.x;
    float4 v = ((const float4*)hidden)[i];
    ushort4 o;
    o.x = f2bf(v.x); o.y = f2bf(v.y); o.z = f2bf(v.z); o.w = f2bf(v.w);
    ((ushort4*)Xb)[i] = o;
    return;
  }
  const float* in; u16* out; int R, Cdim, c0, r0;
  if (b < 6144) {
    int bb = b - 4096;
    in = w_qkv; out = WqkvT; R = 2048; Cdim = 4096;
    c0 = (bb & 63) * 64; r0 = (bb >> 6) * 64;
  } else {
    int bb = b - 6144;
    in = w_o; out = WoT; R = 2048; Cdim = 2048;
    c0 = (bb & 31) * 64; r0 = (bb >> 5) * 64;
  }
  const int tx = threadIdx.x & 63, ty = threadIdx.x >> 6;
#pragma unroll
  for (int i = 0; i < 64; i += 4)
    tile[ty + i][tx] = in[(size_t)(r0 + ty + i) * Cdim + c0 + tx];
  __syncthreads();
#pragma unroll
  for (int i = 0; i < 64; i += 4)
    out[(size_t)(c0 + ty + i) * R + r0 + tx] = f2bf(tile[tx][ty + i]);
}

// sum 2 bf16 partial buffers -> fp32 out
__global__ __launch_bounds__(256) void add_parts2(const u16* __restrict__ a,
                                                  const u16* __restrict__ b,
                                                  float* __restrict__ o, int n4) {
  int i = blockIdx.x * blockDim.x + threadIdx.x;
  if (i < n4) {
    ushort4 x = ((const ushort4*)a)[i], y = ((const ushort4*)b)[i];
    float4 z;
    z.x = bf2f(x.x) + bf2f(y.x);
    z.y = bf2f(x.y) + bf2f(y.y);
    z.z = bf2f(x.z) + bf2f(y.z);
    z.w = bf2f(x.w) + bf2f(y.w);
    ((float4*)o)[i] = z;
  }
}

// ------------------------------------- fused RMSNorm+RoPE and V-transpose
// V is written k-PERMUTED within each 64-token tile (sigma-inv) so the attn
// PV B-fragment (pi contraction order) is one contiguous b128 LDS read.
__global__ __launch_bounds__(256) void rope_vt(const u16* __restrict__ qkv,
                                               const int* __restrict__ pos,
                                               const float* __restrict__ qw,
                                               const float* __restrict__ kw,
                                               u16* __restrict__ Qg,
                                               u16* __restrict__ Kg,
                                               u16* __restrict__ Vt) {
  __shared__ float tile[64][65];
  const int b = blockIdx.x;
  if (b < 12288) {
    const int wave = threadIdx.x >> 6, j = threadIdx.x & 63;
    const int idx = b * 4 + wave;
    const int t = idx & 2047, slot = idx >> 11;
    const float QSC = 0.088388347648318447f * 1.4426950408889634f; // scale*log2e
    const size_t base_i = (size_t)t * 4096 + slot * 128;
    float x1 = bf2f(qkv[base_i + j]);
    float x2 = bf2f(qkv[base_i + j + 64]);
    float ss = x1 * x1 + x2 * x2;
#pragma unroll
    for (int m = 1; m < 64; m <<= 1) ss += __shfl_xor(ss, m);
    float r = rsqrtf(ss * (1.0f / 128.0f) + 1e-6f);
    const bool isq = slot < NH;
    const float* w = isq ? qw : kw;
    float xn1 = x1 * r * w[j], xn2 = x2 * r * w[j + 64];
    float fp = (float)pos[t];
    float inv_freq = exp2f(-(float)j * (13.287712379549449f / 64.0f)); // 10000^(-j/64)
    float ang = fp * inv_freq;
    float sn, cs;
    sincosf(ang, &sn, &cs);
    float o1 = xn1 * cs - xn2 * sn;
    float o2 = xn2 * cs + xn1 * sn;
    if (isq) {
      size_t base = ((size_t)slot * T_TOK + t) * DH;
      Qg[base + j] = f2bf(o1 * QSC); Qg[base + 64 + j] = f2bf(o2 * QSC);
    } else {
      size_t base = ((size_t)(slot - NH) * T_TOK + t) * DH;
      Kg[base + j] = f2bf(o1); Kg[base + 64 + j] = f2bf(o2);
    }
    return;
  }
  const int bb = b - 12288;
  const int h = bb & 7, rest = bb >> 3;
  const int t0 = (rest & 31) * 64, d0 = (rest >> 5) * 64;
  const int tx = threadIdx.x & 63, ty = threadIdx.x >> 6;
#pragma unroll
  for (int i = 0; i < 64; i += 4) {
    size_t gi = (size_t)(t0 + ty + i) * 4096 + (NH + NKV) * DH + h * DH + d0 + tx;
    tile[ty + i][tx] = bf2f(qkv[gi]);
  }
  __syncthreads();
  // sigma-inv: output position tx holds original k-index sx within the tile
  const int sx = ((tx >> 5) * 2 + ((tx >> 2) & 1)) * 16 + ((tx >> 3) & 3) * 4 + (tx & 3);
#pragma unroll
  for (int i = 0; i < 64; i += 4)
    Vt[((size_t)h * DH + d0 + ty + i) * T_TOK + t0 + tx] = f2bf(tile[sx][ty + i]);
}

// ------------------------------------------------------------- GEMM 128x256
// (unchanged — verified counted-vmcnt pipeline)
__global__ __launch_bounds__(512, 2) void gemm128x256(const u16* __restrict__ A,
                                                      const u16* __restrict__ Bt,
                                                      void* __restrict__ Cout,
                                                      int M, int N, int K,
                                                      int lda, int ldb, int obf16) {
  __shared__ __attribute__((aligned(128))) char lds[98304];

  const int nx = N >> 8, ny = M >> 7;
  const int flat = blockIdx.x;
  const int per = gridDim.x >> 3;
  const int swz = (flat & 7) * per + (flat >> 3);
  const int by = swz % ny;
  const int rest = swz / ny;
  const int bx = rest % nx;
  const int bz = rest / nx;
  const int m0 = by << 7, n0 = bx << 8;
  A += (size_t)bz * K;
  Bt += (size_t)bz * K;

  const int tid = threadIdx.x;
  const int wave = tid >> 6, lane = tid & 63;
  const int l15 = lane & 15, quad = lane >> 4;
  const int wr = wave >> 2, wc = wave & 3;

  size_t aoff;
  {
    int chunk = tid;
    int line = chunk >> 3;
    int ls8 = (chunk & 7) ^ (line & 7);
    int row = line * 2 + (ls8 >> 2);
    int ks = ls8 & 3;
    aoff = (size_t)(m0 + row) * lda + ks * 8;
  }
  size_t boff[2];
#pragma unroll
  for (int c = 0; c < 2; ++c) {
    int chunk = c * 512 + tid;
    int line = chunk >> 3;
    int ls8 = (chunk & 7) ^ (line & 7);
    int row = line * 2 + (ls8 >> 2);
    int ks = ls8 & 3;
    boff[c] = (size_t)(n0 + row) * ldb + ks * 8;
  }

#define STAGE(tt) do {                                                   \
    char* da = lds + ((tt) & 3) * 8192 + wave * 1024;                    \
    char* db = lds + 32768 + ((tt) & 3) * 16384 + wave * 1024;           \
    const int kk = (tt) * 32;                                            \
    gload16(A + aoff + kk, da);                                          \
    gload16(Bt + boff[0] + kk, db);                                      \
    gload16(Bt + boff[1] + kk, db + 8192);                               \
  } while (0)

  const int fragoff = (l15 >> 1) * 128 +
                      (((((l15 & 1) << 2) | quad) ^ ((l15 >> 1) & 7)) << 4);

  const f32x4 zero = {0.f, 0.f, 0.f, 0.f};
  f32x4 acc[4][4];
#pragma unroll
  for (int i = 0; i < 4; ++i)
#pragma unroll
    for (int j = 0; j < 4; ++j) acc[i][j] = zero;

  const int NT = K >> 5;
  STAGE(0); STAGE(1); STAGE(2);
  asm volatile("s_waitcnt vmcnt(6)" ::: "memory");
  __builtin_amdgcn_s_barrier();

  for (int t = 0; t < NT; ++t) {
    const char* As = lds + (t & 3) * 8192 + wr * 4096 + fragoff;
    const char* Bs = lds + 32768 + (t & 3) * 16384 + wc * 4096 + fragoff;
    bf16x8 af[4], bfr[4];
#pragma unroll
    for (int mt = 0; mt < 4; ++mt) af[mt] = *(const bf16x8*)(As + mt * 1024);
#pragma unroll
    for (int nt = 0; nt < 4; ++nt) bfr[nt] = *(const bf16x8*)(Bs + nt * 1024);

    if (t + 3 < NT) STAGE(t + 3);

    __builtin_amdgcn_s_setprio(1);
#pragma unroll
    for (int mt = 0; mt < 4; ++mt)
#pragma unroll
      for (int nt = 0; nt < 4; ++nt)
        acc[mt][nt] = __builtin_amdgcn_mfma_f32_16x16x32_bf16(af[mt], bfr[nt], acc[mt][nt], 0, 0, 0);
    __builtin_amdgcn_s_setprio(0);

    const int rem = NT - 1 - t;
    if (rem >= 3)      asm volatile("s_waitcnt vmcnt(6)" ::: "memory");
    else if (rem == 2) asm volatile("s_waitcnt vmcnt(3)" ::: "memory");
    else if (rem == 1) asm volatile("s_waitcnt vmcnt(0)" ::: "memory");
    if (rem > 0) __builtin_amdgcn_s_barrier();
  }
#undef STAGE

  if (obf16) {
    u16* C = (u16*)Cout + (size_t)bz * M * N;
#pragma unroll
    for (int mt = 0; mt < 4; ++mt)
#pragma unroll
      for (int nt = 0; nt < 4; ++nt)
#pragma unroll
        for (int r = 0; r < 4; ++r)
          C[(size_t)(m0 + wr * 64 + mt * 16 + quad * 4 + r) * N + n0 + wc * 64 + nt * 16 + l15] =
              f2bf(acc[mt][nt][r]);
  } else {
    float* C = (float*)Cout + (size_t)bz * M * N;
#pragma unroll
    for (int mt = 0; mt < 4; ++mt)
#pragma unroll
      for (int nt = 0; nt < 4; ++nt)
#pragma unroll
        for (int r = 0; r < 4; ++r)
          C[(size_t)(m0 + wr * 64 + mt * 16 + quad * 4 + r) * N + n0 + wc * 64 + nt * 16 + l15] =
              acc[mt][nt][r];
  }
}

// ------------------------------------------------------------- flash attn
// Paired direct-output: block b = (h, p) computes q-tiles {31-p} (waves 0-3)
// and {p} (waves 4-7) of head h. Work = 33 tile-units/block, constant ->
// perfectly balanced, NO kv-split, NO merge kernel, NO fp32 partials.
// K/V staged once per tile serve both q-tile groups. Per-wave math identical
// to verified R6: swapped QK^T, in-register pi-packed P, V k-permuted in
// global so PV vf is one conflict-free b128 read. In-kernel normalization
// (each block owns full k-range) -> bf16 AttnO written directly.
// 256 blocks (1/CU, all resident), 512 threads, LDS 64 KB.
__global__ __launch_bounds__(512) void attn_kernel(const u16* __restrict__ Qg,
                                                   const u16* __restrict__ Kg,
                                                   const u16* __restrict__ Vtg,
                                                   u16* __restrict__ Og) {
  __shared__ u16 Klds[2][64 * 128];    // [s][d], 16B group g at g^(s&15)
  __shared__ u16 Vlds[2][128 * 64];    // [d][p], 16B group g at g^(d&7), p = pi-order
  const int tid = threadIdx.x;
  const int wave = tid >> 6, lane = tid & 63;
  const int l15 = lane & 15, quad = lane >> 4;
  const int b = blockIdx.x;
  const int h = b & 15, pr = b >> 4;
  const int kvh = h >> 1;
  const int qtLO = pr, qtHI = 31 - pr;
  const int myqt = (wave < 4) ? qtHI : qtLO;  // this wave's q-tile
  const int w4 = wave & 3;
  const int jmax = qtHI + 1;                  // staged tiles (17..32)
  const f32x4 zero = {0.f, 0.f, 0.f, 0.f};

  const u16* Qh = Qg + (size_t)h * T_TOK * DH;
  const u16* Kh = Kg + (size_t)kvh * T_TOK * DH;
  const u16* Vh = Vtg + (size_t)kvh * DH * T_TOK;
  const int qrow0 = myqt * 64 + w4 * 16;

#define STAGEKV(jj, sl) do {                                            \
    u16* Kd = &Klds[sl][0]; u16* Vd = &Vlds[sl][0];                     \
    _Pragma("unroll")                                                   \
    for (int c = 0; c < 2; ++c) {                                       \
      int chunk = wave * 2 + c;                                         \
      int sL = chunk * 64 + lane;                                       \
      { int ss = sL >> 4;                                               \
        int g = (sL & 15) ^ (ss & 15);                                  \
        gload16(Kh + ((size_t)((jj) * 64 + ss)) * DH + g * 8, Kd + chunk * 512); } \
      { int d = sL >> 3;                                                \
        int g = (sL & 7) ^ (d & 7);                                     \
        gload16(Vh + (size_t)d * T_TOK + (jj) * 64 + g * 8, Vd + chunk * 512); } \
    } } while (0)

  bf16x8 qf[4];
#pragma unroll
  for (int ks = 0; ks < 4; ++ks)
    qf[ks] = *(const bf16x8*)(Qh + (size_t)(qrow0 + l15) * DH + ks * 32 + quad * 8);

  f32x4 oacc[8];
#pragma unroll
  for (int i = 0; i < 8; ++i) oacc[i] = zero;
  float l_acc = 0.f;                    // partial l for q=l15 over this lane's k-slots

  // prologue: stage first tile, drain, make visible
  STAGEKV(0, 0);
  asm volatile("s_waitcnt vmcnt(0)" ::: "memory");
  __builtin_amdgcn_s_barrier();

  for (int j = 0; j < jmax; ++j) {
    const int sl = j & 1;
    const bool more = (j + 1 < jmax);
    if (more) STAGEKV(j + 1, sl ^ 1);   // issue-early into other slot
    if (j <= myqt) {                    // my q-tile still consumes this KV tile
      const u16* Kl = &Klds[sl][0];
      const u16* Vl = &Vlds[sl][0];

      // S' = K (Q*scale*log2e)^T : sacc[nt][r] = S[k=j*64+nt*16+quad*4+r][q=qrow0+l15]
      f32x4 sacc[4];
#pragma unroll
      for (int nt = 0; nt < 4; ++nt) sacc[nt] = zero;
      __builtin_amdgcn_s_setprio(1);
#pragma unroll
      for (int nt = 0; nt < 4; ++nt) {
        int sr = nt * 16 + l15;
#pragma unroll
        for (int ks = 0; ks < 4; ++ks) {
          bf16x8 kf = *(const bf16x8*)&Kl[sr * 128 + (((ks * 4 + quad) ^ (sr & 15)) * 8)];
          sacc[nt] = __builtin_amdgcn_mfma_f32_16x16x32_bf16(kf, qf[ks], sacc[nt], 0, 0, 0);
        }
      }
      __builtin_amdgcn_s_setprio(0);

      if (j >= myqt) {                  // diagonal tile: causal mask (swapped indices)
        int q = qrow0 + l15;
#pragma unroll
        for (int nt = 0; nt < 4; ++nt)
#pragma unroll
          for (int r = 0; r < 4; ++r) {
            int k = j * 64 + nt * 16 + quad * 4 + r;
            if (k > q) sacc[nt][r] = -INFINITY;
          }
      }

      // P = exp2(S') truncated to bf16, packed IN REGISTERS as PV A-frags.
      // pa[ks] slot e holds P[q=l15][k = (ks*2+(e>>2))*16 + quad*4 + (e&3)].
      union { unsigned d[4]; bf16x8 v; } pa[2];
#pragma unroll
      for (int ks = 0; ks < 2; ++ks)
#pragma unroll
        for (int w = 0; w < 4; ++w) {
          int nt = ks * 2 + (w >> 1), rp = (w & 1) * 2;
          unsigned ulo = __float_as_uint(exp2f(sacc[nt][rp]));
          unsigned uhi = __float_as_uint(exp2f(sacc[nt][rp + 1]));
          l_acc += __uint_as_float(ulo & 0xffff0000u) + __uint_as_float(uhi & 0xffff0000u);
          pa[ks].d[w] = (ulo >> 16) | (uhi & 0xffff0000u);
        }

      // O += P V; V content already pi-permuted -> single b128 per fragment
      __builtin_amdgcn_s_setprio(1);
#pragma unroll
      for (int ot = 0; ot < 8; ++ot) {
        int d = ot * 16 + l15;
#pragma unroll
        for (int ks = 0; ks < 2; ++ks) {
          bf16x8 vf = *(const bf16x8*)&Vl[d * 64 + (((ks * 4 + quad) ^ (d & 7)) * 8)];
          oacc[ot] = __builtin_amdgcn_mfma_f32_16x16x32_bf16(pa[ks].v, vf, oacc[ot], 0, 0, 0);
        }
      }
      __builtin_amdgcn_s_setprio(0);
    }

    if (more) {                         // next tile landed; make visible
      asm volatile("s_waitcnt vmcnt(0)" ::: "memory");
      __builtin_amdgcn_s_barrier();
    }
  }

  // epilogue: reduce l across quads (all lanes get full l for q=l15), then
  // fetch l for own C/D rows (q = quad*4+r) and write normalized bf16 output.
  l_acc += __shfl_xor(l_acc, 16);
  l_acc += __shfl_xor(l_acc, 32);
  float rl[4];
#pragma unroll
  for (int r = 0; r < 4; ++r)
    rl[r] = 1.0f / __shfl(l_acc, quad * 4 + r);
#pragma unroll
  for (int ot = 0; ot < 8; ++ot)
#pragma unroll
    for (int r = 0; r < 4; ++r)
      Og[(size_t)(qrow0 + quad * 4 + r) * (NH * DH) + h * DH + ot * 16 + l15] =
          f2bf(oacc[ot][r] * rl[r]);
#undef STAGEKV
}

// ------------------------------------------------------------------ launch
extern "C" void kernel_launch(void* const* d_in, const int* in_sizes, int n_in,
                              void* d_out, int out_size, void* d_ws, size_t ws_size,
                              hipStream_t stream) {
  (void)in_sizes; (void)n_in; (void)out_size; (void)ws_size;
  const int* positions = (const int*)d_in[0];
  const float* hidden  = (const float*)d_in[1];
  const float* w_qkv   = (const float*)d_in[2];
  const float* w_o     = (const float*)d_in[3];
  const float* q_norm  = (const float*)d_in[4];
  const float* k_norm  = (const float*)d_in[5];
  float* out = (float*)d_out;

  char* ws = (char*)d_ws;                             // peak use 64 MiB
  u16*   Xb    = (u16*)(ws);                          //  8 MiB [dead after GEMM1]
  u16*   WqkvT = (u16*)(ws + ( 8ull << 20));          // 16 MiB [dead after GEMM1]
  u16*   WoT   = (u16*)(ws + (24ull << 20));          //  8 MiB [live till GEMM2]
  u16*   P0    = (u16*)(ws + (32ull << 20));          // 16 MiB: GEMM1 bf16 out (no split)
  // after GEMM1, WqkvT region dead -> Q/K/V live there:
  u16*   Qg    = (u16*)(ws + ( 8ull << 20));          //  8 MiB bf16 [NH][T][D]
  u16*   Kg    = (u16*)(ws + (16ull << 20));          //  4 MiB bf16 [NKV][T][D]
  u16*   Vt    = (u16*)(ws + (20ull << 20));          //  4 MiB bf16 [NKV][D][T] (k-permuted)
  u16*   AttnO = (u16*)(ws + (48ull << 20));          //  8 MiB bf16 [T][NH*D]
  // after rope_vt, P0 region reused:
  u16*   G2P   = (u16*)(ws + (32ull << 20));          // 16 MiB: GEMM2 bf16 partials (2 x 8 MiB)

  prepass<<<dim3(7168), 256, 0, stream>>>(hidden, w_qkv, w_o, Xb, WqkvT, WoT);

  // QKV proj: 128x256 tiles, NO split-K -> 16x16 = 256 blocks (1/CU)
  gemm128x256<<<dim3(256), 512, 0, stream>>>(
      Xb, WqkvT, P0, T_TOK, 4096, HIDDEN, HIDDEN, HIDDEN, 1);

  rope_vt<<<dim3(12288 + 512), 256, 0, stream>>>(P0, positions,
                                                 q_norm, k_norm, Qg, Kg, Vt);

  // paired direct-output attention: 256 blocks = (h, pair), writes AttnO bf16
  attn_kernel<<<dim3(256), 512, 0, stream>>>(Qg, Kg, Vt, AttnO);

  // O-proj: 128x256 tiles, split-K=2 -> 16x8x2 = 256 blocks (1/CU)
  gemm128x256<<<dim3(256), 512, 0, stream>>>(
      AttnO, WoT, G2P, T_TOK, HIDDEN, 1024, NH * DH, NH * DH, 1);
  const int n4 = T_TOK * HIDDEN / 4;
  add_parts2<<<dim3(n4 / 256), 256, 0, stream>>>(
      G2P, G2P + (size_t)T_TOK * HIDDEN, out, n4);
}